// Round 2
// baseline (1060.658 us; speedup 1.0000x reference)
//
#include <hip/hip_runtime.h>

// RBF kernel, D=1: out[b,i,j] = exp(-(x1[b,i]-x2[b,j])^2 / (2*s^2)).
// Output = 1 GiB fp32 -> pure HBM-write-bound. Floor ~172 us at fill-measured
// 6.25 TB/s. Rounds 0/1 showed ~330 us regardless of {nt vs plain stores,
// 1-row vs 8-row tiling, OCML vs raw exp} -> the cap is shared structure.
//
// This version: mimic __amd_rocclr_fillBufferAligned (6.25 TB/s on this same
// buffer, same capture) EXACTLY in write-stream shape:
//  - ONE flat linear float4 stream over the whole output, grid-stride;
//    consecutive waves write consecutive 1 KB chunks; the grid advances as a
//    single dense front (vs 4096 scattered per-block cursors before).
//  - 2048 blocks x 256 threads (8 blocks/CU), 128 iters/thread, unroll 4 so
//    4 loads+4 stores in flight per thread.
//  - (row, j4, b) recomputed from the flat index with shifts (pow2 sizes).
// x1/x2 reads are L1/L2-hot (160 KB total inputs) and irrelevant per R1.

#define THREADS 256

typedef float vfloat4 __attribute__((ext_vector_type(4)));

__global__ __launch_bounds__(THREADS) void rbf_flat_kernel(
    const float* __restrict__ x1,
    const float* __restrict__ x2,
    const float* __restrict__ scale,
    float* __restrict__ out,
    int n4_total, int lg_n4row, int lg_N1) {
  const float s  = scale[0];
  // exp(-d^2/(2 s^2)) == exp2(c2 * d^2), c2 = -log2(e)/(2 s^2)
  const float c2 = -1.4426950408889634f / (2.0f * s * s);

  const vfloat4* __restrict__ x2v = (const vfloat4*)x2;
  vfloat4* __restrict__ outv = (vfloat4*)out;

  const int j4mask = (1 << lg_n4row) - 1;
  const int stride = gridDim.x * blockDim.x;

#pragma unroll 4
  for (int idx4 = blockIdx.x * blockDim.x + threadIdx.x; idx4 < n4_total;
       idx4 += stride) {
    const int row = idx4 >> lg_n4row;        // flat b*N1 + i
    const int j4  = idx4 & j4mask;
    const int b   = row >> lg_N1;
    const float a = x1[row];                 // wave-uniform (row spans 32 waves)
    const vfloat4 v = x2v[((size_t)b << lg_n4row) + j4];  // L1/L2-hot
    vfloat4 d, e;
    d.x = a - v.x;
    d.y = a - v.y;
    d.z = a - v.z;
    d.w = a - v.w;
    e.x = __builtin_amdgcn_exp2f(c2 * d.x * d.x);
    e.y = __builtin_amdgcn_exp2f(c2 * d.y * d.y);
    e.z = __builtin_amdgcn_exp2f(c2 * d.z * d.z);
    e.w = __builtin_amdgcn_exp2f(c2 * d.w * d.w);
    outv[idx4] = e;                          // dense linear write front
  }
}

// Generic fallback (non-pow2 shapes): one row per block.
__global__ __launch_bounds__(THREADS) void rbf_row_kernel(
    const float* __restrict__ x1,
    const float* __restrict__ x2,
    const float* __restrict__ scale,
    float* __restrict__ out,
    int N1, int N2) {
  const int row = blockIdx.x;
  const int b   = row / N1;
  const float a = x1[row];
  const float s = scale[0];
  const float c2 = -1.4426950408889634f / (2.0f * s * s);
  const float* x2r = x2 + (size_t)b * N2;
  float* outr = out + (size_t)row * N2;
  for (int j = threadIdx.x; j < N2; j += THREADS) {
    const float d = a - x2r[j];
    outr[j] = __builtin_amdgcn_exp2f(c2 * d * d);
  }
}

static inline bool is_pow2(int v) { return v > 0 && (v & (v - 1)) == 0; }
static inline int ilog2(int v) { int l = 0; while ((1 << l) < v) ++l; return l; }

extern "C" void kernel_launch(void* const* d_in, const int* in_sizes, int n_in,
                              void* d_out, int out_size, void* d_ws, size_t ws_size,
                              hipStream_t stream) {
  const float* x1    = (const float*)d_in[0];
  const float* x2    = (const float*)d_in[1];
  const float* scale = (const float*)d_in[2];
  float* out = (float*)d_out;

  const int B  = 4;                 // per reference setup_inputs()
  const int N1 = in_sizes[0] / B;   // 8192 (D=1)
  const int N2 = in_sizes[1] / B;   // 8192

  if (is_pow2(N1) && is_pow2(N2) && (N2 % 4) == 0 && is_pow2(N2 / 4)) {
    const int n4row = N2 / 4;                      // 2048
    const int n4_total = B * N1 * n4row;           // 2^26 float4
    dim3 grid(2048);                               // 8 blocks/CU, fill-style
    rbf_flat_kernel<<<grid, dim3(THREADS), 0, stream>>>(
        x1, x2, scale, out, n4_total, ilog2(n4row), ilog2(N1));
  } else {
    dim3 grid(B * N1);
    rbf_row_kernel<<<grid, dim3(THREADS), 0, stream>>>(x1, x2, scale, out, N1, N2);
  }
}